// Round 9
// baseline (361.204 us; speedup 1.0000x reference)
//
#include <hip/hip_runtime.h>
#include <cstdint>
#include <cstddef>

// Problem constants (FusedExperts: E=8 TOPK=2, B=2 S=4096 D=1024 H=2048)
#define TT   8192     // tokens = B*S
#define DD   1024     // model dim
#define HH   2048     // hidden dim
#define H2   4096     // 2*H
#define EE   8        // experts
#define PP   16384    // routed pairs = TT*TOPK
#define PADROWS 18432 // max sum of per-expert 256-padded group sizes = 72*256
#define MAXT1 72      // 256-row tiles (gemm1)

typedef unsigned short u16;
typedef __attribute__((ext_vector_type(8))) short bf16x8;   // 8 bf16 = 4 VGPR (MFMA A/B frag)
typedef __attribute__((ext_vector_type(8))) unsigned short u16x8;
typedef __attribute__((ext_vector_type(4))) float f32x4;    // MFMA C/D frag

__device__ __forceinline__ u16 f2bf(float f) {
  unsigned int u = __builtin_bit_cast(unsigned int, f);
  u += 0x7fffu + ((u >> 16) & 1u);          // round-to-nearest-even
  return (u16)(u >> 16);
}
__device__ __forceinline__ float bf2f(u16 s) {
  unsigned int u = ((unsigned int)s) << 16;
  return __builtin_bit_cast(float, u);
}

__device__ __forceinline__ void gload_lds16(const u16* g, u16* l) {
  __builtin_amdgcn_global_load_lds(
      (const __attribute__((address_space(1))) void*)g,
      (__attribute__((address_space(3))) void*)l, 16, 0, 0);
}

#define BAR()    __builtin_amdgcn_s_barrier()
#define LGKM0()  asm volatile("s_waitcnt lgkmcnt(0)")
#define WAITV4() asm volatile("s_waitcnt vmcnt(4)" ::: "memory")
#define WAITV0() asm volatile("s_waitcnt vmcnt(0)" ::: "memory")

// ============ prep: cast_x + transpose-cast w13/w2 + routing, ONE kernel ============
// Block ranges: [0,4096) cast_x; [4096,12288) tcast w13; [12288,16384) tcast w2;
// [16384] routing (single block, LDS histogram). Groups padded to 256 rows.
__global__ __launch_bounds__(256)
void prep_kernel(const float* __restrict__ x, u16* __restrict__ xb,
                 const float* __restrict__ w13, u16* __restrict__ w13t,
                 const float* __restrict__ w2, u16* __restrict__ w2t,
                 const int* __restrict__ eidx, const float* __restrict__ ep,
                 int* __restrict__ pofs, int* __restrict__ ptok,
                 float* __restrict__ pscale, int* __restrict__ ppos) {
  __shared__ __align__(16) u16 tile[32][140];
  __shared__ int hcnt[EE], hbase[EE], hrun[EE];
  const int b = blockIdx.x;
  const int t = threadIdx.x;

  if (b < 4096) {
    const long i = (long)b * 256 + t;
    const f32x4* s = (const f32x4*)(x + i * 8);
    f32x4 a = s[0], c = s[1];
    u16x8 o;
    o[0]=f2bf(a[0]); o[1]=f2bf(a[1]); o[2]=f2bf(a[2]); o[3]=f2bf(a[3]);
    o[4]=f2bf(c[0]); o[5]=f2bf(c[1]); o[6]=f2bf(c[2]); o[7]=f2bf(c[3]);
    *(u16x8*)(xb + i * 8) = o;
    return;
  }

  if (b < 16384) {
    const float* src; u16* dst; int R, C, gx, gy, gz;
    if (b < 12288) {
      const int lb = b - 4096;              // w13: R=DD, C=H2; grid 128x8x8
      src = w13; dst = w13t; R = DD; C = H2;
      gx = lb & 127; gy = (lb >> 7) & 7; gz = lb >> 10;
    } else {
      const int lb = b - 12288;             // w2: R=HH, C=DD; grid 32x16x8
      src = w2; dst = w2t; R = HH; C = DD;
      gx = lb & 31; gy = (lb >> 5) & 15; gz = lb >> 9;
    }
    const long base = (long)gz * (long)R * C;
    const int c0 = gx * 32, r0 = gy * 128;
    {
      const int tx = t & 31, ty = t >> 5;
#pragma unroll
      for (int rr = 0; rr < 16; ++rr) {
        const int r = ty + rr * 8;
        tile[tx][r] = f2bf(src[base + (long)(r0 + r) * C + c0 + tx]);
      }
    }
    __syncthreads();
    {
      const int k = t & 15, cb = t >> 4;
#pragma unroll
      for (int i = 0; i < 2; ++i) {
        const int c = i * 16 + cb;
        u16x8 o = *(const u16x8*)(&tile[c][8 * k]);
        *(u16x8*)(dst + base + (long)(c0 + c) * R + r0 + 8 * k) = o;
      }
    }
    return;
  }

  // ---- routing: single block, 64 pairs/thread; 256-row padding ----
  if (t < EE) { hcnt[t] = 0; hrun[t] = 0; }
  __syncthreads();
#pragma unroll 4
  for (int k = 0; k < 64; ++k) {
    const int i = t * 64 + k;
    atomicAdd(&hcnt[eidx[i]], 1);
  }
  __syncthreads();
  if (t == 0) {
    int run = 0;
#pragma unroll
    for (int e = 0; e < EE; ++e) {
      pofs[e] = run; hbase[e] = run;
      run += ((hcnt[e] + 255) >> 8) << 8;
    }
    pofs[EE] = run;
  }
  __syncthreads();
#pragma unroll 4
  for (int k = 0; k < 64; ++k) {
    const int i = t * 64 + k;
    const int e = eidx[i];
    const int r = atomicAdd(&hrun[e], 1);
    const int pos = hbase[e] + r;
    ptok[pos] = i >> 1;         // token index (TOPK=2)
    pscale[pos] = ep[i];
    ppos[i] = pos;
  }
}

// ============ GEMM1: 256x256 8-phase (R6 schedule, VGPR cap REMOVED) ============
// __launch_bounds__(512) only: 128KB LDS forces 1 block/CU; (512,2) had capped
// the allocator at 128 arch-VGPRs (rocprof showed exactly 128 = at-cap) and
// starved the 176+-reg working set -- the R5/R6 failure cause under test.
#define QUAD(M0, N0) do {                                                        \
    __builtin_amdgcn_s_setprio(1);                                               \
    _Pragma("unroll") for (int mm = 0; mm < 4; ++mm)                             \
    _Pragma("unroll") for (int nn = 0; nn < 2; ++nn)                             \
    _Pragma("unroll") for (int kk = 0; kk < 2; ++kk)                             \
      acc[(M0)+mm][(N0)+nn] = __builtin_amdgcn_mfma_f32_16x16x32_bf16(           \
          af[kk][(M0)+mm], bf[kk][(N0)+nn], acc[(M0)+mm][(N0)+nn], 0, 0, 0);     \
    __builtin_amdgcn_s_setprio(0);                                               \
  } while (0)

__global__ __launch_bounds__(512)
void gemm1_kernel(const u16* __restrict__ xb, const u16* __restrict__ w13t,
                  const int* __restrict__ ptok, const int* __restrict__ pofs,
                  u16* __restrict__ hb) {
  __shared__ __align__(16) u16 lds[65536];   // 128 KB

  // T1 XCD swizzle: nwg = 72*16 = 1152 = 8*144 (exact)
  const int f = blockIdx.y * MAXT1 + blockIdx.x;
  const int wg = (f & 7) * 144 + (f >> 3);
  const int tileIdx = wg % MAXT1;
  const int j = wg / MAXT1;                 // h cols [j*128,+128), g at +HH

  const int ts = tileIdx * 256;
  if (ts >= pofs[EE]) return;
  int e = 0;
#pragma unroll
  for (int i = 1; i < EE; ++i) e += (ts >= pofs[i]) ? 1 : 0;

  const int tid = threadIdx.x;
  const int w = tid >> 6, lane = tid & 63;
  const int wm = w >> 2, wn = w & 3;        // 2 x 4 waves

  const u16* bbase = w13t + (long)e * ((long)H2 * DD);

  // staging: per half-tile ht, 2 instrs i; 16B/lane. [128][64] region.
  int aoffg[2][2]; int boffg[2][2]; int dstA[2][2], dstB[2][2];
#pragma unroll
  for (int ht = 0; ht < 2; ++ht)
#pragma unroll
    for (int i = 0; i < 2; ++i) {
      const int L = tid * 16 + i * 8192;    // byte within region
      const int row = L >> 7;
      const int slot = ((L >> 4) & 7) ^ (row & 7);
      aoffg[ht][i] = ptok[ts + ht * 128 + row] * DD + slot * 8;
      const int r = ht * 128 + row;
      const int wnr = r >> 6, within = r & 63;
      const int grow = (within < 32) ? (j * 128 + wnr * 32 + within)
                                     : (HH + j * 128 + wnr * 32 + within - 32);
      boffg[ht][i] = grow * DD + slot * 8;
      dstA[ht][i] = ht * 8192 + i * 4096 + w * 512;            // + p*16384
      dstB[ht][i] = 32768 + ht * 8192 + i * 4096 + w * 512;
    }

  const int l15 = lane & 15, x7 = lane & 7, sA = lane >> 4;
  int aoff[2][8], boff[2][4];
#pragma unroll
  for (int kk = 0; kk < 2; ++kk) {
    const int sl = ((kk * 4 + sA) ^ x7) * 8;
#pragma unroll
    for (int m = 0; m < 8; ++m) aoff[kk][m] = (m * 16 + l15) * 64 + sl;
#pragma unroll
    for (int n = 0; n < 4; ++n) boff[kk][n] = ((w & 1) * 64 + n * 16 + l15) * 64 + sl;
  }

  f32x4 acc[8][4];
#pragma unroll
  for (int m = 0; m < 8; ++m)
#pragma unroll
    for (int n = 0; n < 4; ++n) acc[m][n] = (f32x4){0.f, 0.f, 0.f, 0.f};

  auto stageA = [&](int t, int p, int ht) {
    const int k0 = t * 64;
    gload_lds16(xb + aoffg[ht][0] + k0, lds + p * 16384 + dstA[ht][0]);
    gload_lds16(xb + aoffg[ht][1] + k0, lds + p * 16384 + dstA[ht][1]);
  };
  auto stageB = [&](int t, int p, int ht) {
    const int k0 = t * 64;
    gload_lds16(bbase + boffg[ht][0] + k0, lds + p * 16384 + dstB[ht][0]);
    gload_lds16(bbase + boffg[ht][1] + k0, lds + p * 16384 + dstB[ht][1]);
  };

  bf16x8 af[2][8], bf[2][4];

  // prologue: A(0),B(0),A(1) = 12 loads; vmcnt(4) -> K-tile 0 fully landed
  stageA(0, 0, 0); stageA(0, 0, 1); stageB(0, 0, 0); stageB(0, 0, 1);
  stageA(1, 1, 0); stageA(1, 1, 1);
  WAITV4(); BAR();

  for (int t = 0; t < 16; ++t) {
    const int p = t & 1;
    const bool stB = t < 15, stA = t < 14;
    const u16* Areg = lds + p * 16384 + wm * 8192;
    const u16* Breg = lds + 32768 + p * 16384 + (wn >> 1) * 8192;
    // ---- P0: ds a[0..3], b[0..1]; stage B0(t+1) ----
#pragma unroll
    for (int kk = 0; kk < 2; ++kk) {
#pragma unroll
      for (int m = 0; m < 4; ++m) af[kk][m] = *(const bf16x8*)(Areg + aoff[kk][m]);
#pragma unroll
      for (int n = 0; n < 2; ++n) bf[kk][n] = *(const bf16x8*)(Breg + boff[kk][n]);
    }
    if (stB) stageB(t + 1, p ^ 1, 0);
    BAR(); LGKM0();
    QUAD(0, 0);
    BAR();
    // ---- P1: ds a[4..7]; stage B1(t+1) ----
#pragma unroll
    for (int kk = 0; kk < 2; ++kk)
#pragma unroll
      for (int m = 4; m < 8; ++m) af[kk][m] = *(const bf16x8*)(Areg + aoff[kk][m]);
    if (stB) stageB(t + 1, p ^ 1, 1);
    BAR(); LGKM0();
    QUAD(4, 0);
    BAR();
    // ---- P2: ds b[2..3]; stage A0(t+2) ----
#pragma unroll
    for (int kk = 0; kk < 2; ++kk)
#pragma unroll
      for (int n = 2; n < 4; ++n) bf[kk][n] = *(const bf16x8*)(Breg + boff[kk][n]);
    if (stA) stageA(t + 2, p, 0);
    BAR(); LGKM0();
    QUAD(4, 2);
    BAR();
    // ---- P3: stage A1(t+2); tail vmcnt ----
    if (stA) stageA(t + 2, p, 1);
    BAR();
    QUAD(0, 2);
    if (t < 14) { WAITV4(); } else if (t == 14) { WAITV0(); }
    BAR();
  }

  // epilogue: silu(g)*h in registers (n and n+2 share output col)
#pragma unroll
  for (int m = 0; m < 8; ++m)
#pragma unroll
    for (int n = 0; n < 2; ++n) {
      const int col = j * 128 + wn * 32 + n * 16 + l15;
#pragma unroll
      for (int r = 0; r < 4; ++r) {
        const int row = ts + wm * 128 + m * 16 + sA * 4 + r;
        const float h = acc[m][n][r];
        const float g = acc[m][n + 2][r];
        hb[(long)row * HH + col] = f2bf(h * (g / (1.f + __expf(-g))));
      }
    }
}

// ============ GEMM2: 128x256 tile, XCD j/half-split (R8), 144 tiles ============
__global__ __launch_bounds__(256, 2)
void gemm2_kernel(const u16* __restrict__ hb, const u16* __restrict__ w2t,
                  const float* __restrict__ pscale, const int* __restrict__ pofs,
                  u16* __restrict__ ye) {
  __shared__ __align__(16) u16 lds_a[128 * 64];
  __shared__ __align__(16) u16 lds_b[256 * 64];

  // 576 blocks = 8 XCD-chunks of 72: k8 -> (j = k8>>1, half = k8&1)
  const int f = blockIdx.y * 72 + blockIdx.x;
  const int k8 = f & 7, idx = f >> 3;       // idx 0..71
  const int tileIdx = (k8 & 1) * 72 + idx;  // 0..143
  const int j = k8 >> 1;                    // 0..3: out cols [j*256, +256)

  const int ts = tileIdx * 128;
  if (ts >= pofs[EE]) return;
  int e = 0;
#pragma unroll
  for (int i = 1; i < EE; ++i) e += (ts >= pofs[i]) ? 1 : 0;

  const int tid = threadIdx.x;
  const int w = tid >> 6, lane = tid & 63;
  const int wr = w >> 1, wc = w & 1;

  const u16* bbase = w2t + (long)e * ((long)DD * HH);

  const u16* asrc[4]; const u16* bsrc[8];
  u16* adst[4]; u16* bdst[8];
#pragma unroll
  for (int r = 0; r < 4; ++r) {
    const int L = r * 4096 + tid * 16;
    const int row = L >> 7;
    const int slot = ((L >> 4) & 7) ^ (row & 7);
    asrc[r] = hb + (long)(ts + row) * HH + slot * 8;
    adst[r] = lds_a + r * 2048 + w * 512;
  }
#pragma unroll
  for (int r = 0; r < 8; ++r) {
    const int L = r * 4096 + tid * 16;
    const int row = L >> 7;                              // 0..255
    const int slot = ((L >> 4) & 7) ^ (row & 7);
    bsrc[r] = bbase + (long)(j * 256 + row) * HH + slot * 8;
    bdst[r] = lds_b + r * 2048 + w * 512;
  }

  const int l15 = lane & 15, x7 = lane & 7, sA = lane >> 4;
  int aoff[2][4], boff[2][8];
#pragma unroll
  for (int kk = 0; kk < 2; ++kk) {
    const int sl = ((kk * 4 + sA) ^ x7) * 8;
#pragma unroll
    for (int m = 0; m < 4; ++m) aoff[kk][m] = (wr * 64 + m * 16 + l15) * 64 + sl;
#pragma unroll
    for (int n = 0; n < 8; ++n) boff[kk][n] = (wc * 128 + n * 16 + l15) * 64 + sl;
  }

  f32x4 acc[4][8];
#pragma unroll
  for (int m = 0; m < 4; ++m)
#pragma unroll
    for (int n = 0; n < 8; ++n) acc[m][n] = (f32x4){0.f, 0.f, 0.f, 0.f};

  for (int k0 = 0; k0 < HH; k0 += 64) {
#pragma unroll
    for (int r = 0; r < 4; ++r) gload_lds16(asrc[r] + k0, adst[r]);
#pragma unroll
    for (int r = 0; r < 8; ++r) gload_lds16(bsrc[r] + k0, bdst[r]);
    __syncthreads();

    bf16x8 af[2][4], bfr[2][8];
#pragma unroll
    for (int kk = 0; kk < 2; ++kk) {
#pragma unroll
      for (int m = 0; m < 4; ++m) af[kk][m] = *(const bf16x8*)(lds_a + aoff[kk][m]);
#pragma unroll
      for (int n = 0; n < 8; ++n) bfr[kk][n] = *(const bf16x8*)(lds_b + boff[kk][n]);
    }
#pragma unroll
    for (int m = 0; m < 4; ++m)
#pragma unroll
      for (int n = 0; n < 8; ++n)
#pragma unroll
        for (int kk = 0; kk < 2; ++kk)
          acc[m][n] = __builtin_amdgcn_mfma_f32_16x16x32_bf16(af[kk][m], bfr[kk][n], acc[m][n], 0, 0, 0);
    __syncthreads();
  }

#pragma unroll
  for (int m = 0; m < 4; ++m)
#pragma unroll
    for (int r = 0; r < 4; ++r) {
      const int row = ts + wr * 64 + m * 16 + sA * 4 + r;
      const float sc = pscale[row];   // 0.0 for pad rows
#pragma unroll
      for (int n = 0; n < 8; ++n) {
        const int col = j * 256 + wc * 128 + n * 16 + l15;
        ye[(long)row * DD + col] = f2bf(acc[m][n][r] * sc);
      }
    }
}

// ---------------- combine: y[t] = ye[pos0] + ye[pos1] ----------------
__global__ void combine_kernel(const u16* __restrict__ ye, const int* __restrict__ ppos,
                               float* __restrict__ y) {
  const long i = (long)blockIdx.x * 256 + threadIdx.x;  // one thread -> 8 outputs
  const int t = (int)(i >> 7);
  const int c = ((int)i & 127) * 8;
  const int p0 = ppos[t * 2], p1 = ppos[t * 2 + 1];
  u16x8 v0 = *(const u16x8*)(ye + (long)p0 * DD + c);
  u16x8 v1 = *(const u16x8*)(ye + (long)p1 * DD + c);
  f32x4 o0, o1;
  o0[0] = bf2f(v0[0]) + bf2f(v1[0]);
  o0[1] = bf2f(v0[1]) + bf2f(v1[1]);
  o0[2] = bf2f(v0[2]) + bf2f(v1[2]);
  o0[3] = bf2f(v0[3]) + bf2f(v1[3]);
  o1[0] = bf2f(v0[4]) + bf2f(v1[4]);
  o1[1] = bf2f(v0[5]) + bf2f(v1[5]);
  o1[2] = bf2f(v0[6]) + bf2f(v1[6]);
  o1[3] = bf2f(v0[7]) + bf2f(v1[7]);
  *(f32x4*)(y + (long)t * DD + c) = o0;
  *(f32x4*)(y + (long)t * DD + c + 4) = o1;
}

extern "C" void kernel_launch(void* const* d_in, const int* in_sizes, int n_in,
                              void* d_out, int out_size, void* d_ws, size_t ws_size,
                              hipStream_t stream) {
  const float* x    = (const float*)d_in[0];
  const float* ep   = (const float*)d_in[1];
  const int*   eidx = (const int*)d_in[2];
  const float* w13  = (const float*)d_in[3];
  const float* w2   = (const float*)d_in[4];
  float* y = (float*)d_out;

  char* ws = (char*)d_ws;
  size_t off = 0;
  auto alloc = [&](size_t bytes) {
    char* p = ws + off;
    off = (off + bytes + 255) & ~(size_t)255;
    return p;
  };
  u16* xb     = (u16*)alloc((size_t)TT * DD * 2);
  u16* w13t   = (u16*)alloc((size_t)EE * H2 * DD * 2);
  u16* w2t    = (u16*)alloc((size_t)EE * DD * HH * 2);
  u16* hb     = (u16*)alloc((size_t)PADROWS * HH * 2);
  u16* ye     = (u16*)alloc((size_t)PADROWS * DD * 2);
  char* zbase = ws + off;
  int*   ptok   = (int*)alloc((size_t)PADROWS * 4);
  float* pscale = (float*)alloc((size_t)PADROWS * 4);
  size_t zbytes = (size_t)((ws + off) - zbase);
  int*   pofs   = (int*)alloc((EE + 1) * 4);
  int*   ppos   = (int*)alloc((size_t)PP * 4);
  (void)ws_size; (void)in_sizes; (void)n_in; (void)out_size;

  // zero routing state (pad rows -> token 0, scale 0)
  hipMemsetAsync(zbase, 0, zbytes, stream);

  // fused prep: cast_x + tcast(w13) + tcast(w2) + routing
  prep_kernel<<<16385, 256, 0, stream>>>(x, xb, w13, w13t, w2, w2t,
                                         eidx, ep, pofs, ptok, pscale, ppos);

  gemm1_kernel<<<dim3(MAXT1, HH / 128), 512, 0, stream>>>(xb, w13t, ptok, pofs, hb);
  gemm2_kernel<<<dim3(72, 8), 256, 0, stream>>>(hb, w2t, pscale, pofs, ye);
  combine_kernel<<<4096, 256, 0, stream>>>(ye, ppos, y);
}